// Round 7
// baseline (72.331 us; speedup 1.0000x reference)
//
#include <hip/hip_runtime.h>

typedef __attribute__((ext_vector_type(8))) short short8;
typedef __attribute__((ext_vector_type(4))) float f32x4;
typedef __attribute__((ext_vector_type(4))) int   i32x4;

#define IN_F   4096
#define OUT_F  16384
#define NG     32
#define BKI    256          // ints per chunk per row (1 KB granule)
#define NCH    16           // chunks (4096/256)
#define BN     16           // out-cols per block

// f32 -> bf16 round-to-nearest-even
static __device__ __forceinline__ short f2bf(float f) {
    union { float f; unsigned u; } c; c.f = f;
    unsigned u = c.u;
    u += 0x7FFF + ((u >> 16) & 1);
    return (short)(u >> 16);
}

// int8-range -> bf16 (exact for |v| <= 127)
static __device__ __forceinline__ short i2bf(int v) {
    union { float f; unsigned u; } c; c.f = (float)v;
    return (short)(c.u >> 16);
}

// Pre-pass: x[32][4096] f32 -> xT bf16 in MFMA-A-fragment order.
// xT layout: [t][h][ln][8] bf16, t = k/32, h = m-half, ln = l15*4 + l4.
__global__ __launch_bounds__(256)
void xconv_kernel(const float* __restrict__ x, unsigned short* __restrict__ xT) {
    const int g   = blockIdx.x * 256 + threadIdx.x;   // 16384 threads
    const int t   = g >> 7;
    const int rem = g & 127;
    const int h   = rem >> 6;
    const int ln  = rem & 63;
    const int l15 = ln >> 2;
    const int l4  = ln & 3;
    const float* src = x + (size_t)(16 * h + l15) * IN_F + t * 32 + l4 * 8;
    f32x4 a = *(const f32x4*)src;
    f32x4 b = *(const f32x4*)(src + 4);
    short8 o;
#pragma unroll
    for (int j = 0; j < 4; ++j) { o[j] = f2bf(a[j]); o[j + 4] = f2bf(b[j]); }
    *(short8*)(xT + (size_t)g * 8) = o;
}

// Main: 512 thr = 8 waves. Block owns 16 out-cols, full K.
// Wave = (wm, q): wm = m-half of the 32x16 output, q = K-quarter (64 ints)
// within each 256-int chunk. Staging: per chunk, 16 rows x 1 KB contiguous,
// one global_load_lds per row (2 per wave). Counted-vmcnt 3-slot pipeline.
__global__ __launch_bounds__(512, 4)
void qlin_kernel(const unsigned short* __restrict__ xT,
                 const int*   __restrict__ qw,
                 const float* __restrict__ scales,
                 const float* __restrict__ bias,
                 float*       __restrict__ out)
{
    __shared__ int lqw[3][BN][BKI];     // 48 KB; aliased as `red` in epilogue

    const int tid  = threadIdx.x;
    const int wv   = tid >> 6;
    const int lane = tid & 63;
    const int l15  = lane & 15;
    const int l4   = lane >> 4;
    const int q    = wv & 3;          // K-quarter within chunk
    const int wm   = wv >> 2;         // m-half
    const int col0 = blockIdx.x * BN;

    const int swz = (l15 & 7) << 4;

    // --- stage chunk c into slot sl: rows 2wv, 2wv+1, 1 KB contiguous each ---
    // Source pre-swizzled by ((row&7)<<4): permutes 16B blocks inside the 1 KB
    // span (contiguity preserved); read applies the same XOR (rule #21).
    auto STAGE = [&](int c, int sl) {
#pragma unroll
        for (int i = 0; i < 2; ++i) {
            const int row = 2 * wv + i;
            const int byt = (lane * 16) ^ ((row & 7) << 4);
            const char* src = (const char*)(qw + (size_t)(col0 + row) * IN_F + c * BKI) + byt;
            __builtin_amdgcn_global_load_lds(
                (const __attribute__((address_space(1))) unsigned int*)src,
                (__attribute__((address_space(3))) unsigned int*)&lqw[sl][row][0],
                16, 0, 0);
        }
    };

    // --- x fragments: distance-2 register prefetch ---
    // k-tile for (c, q, s) = c*8 + q*2 + s
    const unsigned short* xgrp = xT + (size_t)(l15 * 4 + l4) * 8 + (size_t)wm * 512;
    short8 xa[2][2];                   // [parity][step]
    auto XLOAD = [&](int c, int par) {
        const int t = c * 8 + q * 2;
        xa[par][0] = *(const short8*)(xgrp + (size_t)t * 1024);
        xa[par][1] = *(const short8*)(xgrp + (size_t)(t + 1) * 1024);
    };

    // --- scales: group for (c,q) = 2c + (q>>1); preload all 16 (static idx) ---
    const float* scr = scales + (size_t)(col0 + l15) * NG + (q >> 1);
    float sc_arr[16];
#pragma unroll
    for (int j = 0; j < 16; ++j) sc_arr[j] = scr[2 * j];

    f32x4 acc = {0.f, 0.f, 0.f, 0.f};

    // --- compute chunk c from slot sl (quarter q of the 256 ints) ---
    auto COMPUTE = [&](int c, int sl, int par, float sc) {
        const char* lrow = (const char*)&lqw[sl][l15][0];
        f32x4 ag = {0.f, 0.f, 0.f, 0.f};
#pragma unroll
        for (int s = 0; s < 2; ++s) {
            const int off = (q * 256 + s * 128 + l4 * 32) ^ swz;
            i32x4 q0 = *(const i32x4*)(lrow + off);
            i32x4 q1 = *(const i32x4*)(lrow + (off ^ 16));
            short8 bfr;
#pragma unroll
            for (int j = 0; j < 4; ++j) { bfr[j] = i2bf(q0[j]); bfr[j + 4] = i2bf(q1[j]); }
            ag = __builtin_amdgcn_mfma_f32_16x16x32_bf16(xa[par][s], bfr, ag, 0, 0, 0);
        }
#pragma unroll
        for (int r = 0; r < 4; ++r) acc[r] += sc * ag[r];
    };

    // --- prologue: x(0),x(1), stage(0),stage(1); vmcnt(2) keeps stage(1) ---
    XLOAD(0, 0);
    XLOAD(1, 1);
    asm volatile("" ::: "memory");     // pin: x-loads issue before stages
    STAGE(0, 0);
    STAGE(1, 1);
    asm volatile("s_waitcnt vmcnt(2)" ::: "memory");
    __builtin_amdgcn_s_barrier();
    __builtin_amdgcn_sched_barrier(0);

    // --- steady: compute(i) || {x(i+2), stage(i+2)}; vmcnt(4), never 0 ---
#pragma unroll
    for (int i = 0; i <= 13; ++i) {
        COMPUTE(i, i % 3, i & 1, sc_arr[i]);
        XLOAD(i + 2, i & 1);
        asm volatile("" ::: "memory");
        STAGE(i + 2, (i + 2) % 3);
        asm volatile("s_waitcnt vmcnt(4)" ::: "memory");
        __builtin_amdgcn_s_barrier();
        __builtin_amdgcn_sched_barrier(0);
    }
    COMPUTE(14, 14 % 3, 0, sc_arr[14]);
    asm volatile("s_waitcnt vmcnt(0)" ::: "memory");
    __builtin_amdgcn_s_barrier();
    __builtin_amdgcn_sched_barrier(0);
    COMPUTE(15, 15 % 3, 1, sc_arr[15]);

    // --- epilogue: 4-way cross-quarter reduce through aliased LDS ---
    __syncthreads();
    float* red = (float*)&lqw[0][0][0];       // [8][64][4] = 8 KB
    *(f32x4*)&red[(size_t)(wv * 64 + lane) * 4] = acc;
    __syncthreads();
    if (q == 0) {                              // waves 0 and 4
        f32x4 s = *(const f32x4*)&red[(size_t)(wv * 64 + lane) * 4];
#pragma unroll
        for (int w = 1; w < 4; ++w) {
            f32x4 t = *(const f32x4*)&red[(size_t)((wv + w) * 64 + lane) * 4];
#pragma unroll
            for (int r = 0; r < 4; ++r) s[r] += t[r];
        }
        const int col = col0 + l15;
        const float bv = bias[col];
#pragma unroll
        for (int r = 0; r < 4; ++r)
            out[(size_t)(16 * wm + l4 * 4 + r) * OUT_F + col] = s[r] + bv;
    }
}

extern "C" void kernel_launch(void* const* d_in, const int* in_sizes, int n_in,
                              void* d_out, int out_size, void* d_ws, size_t ws_size,
                              hipStream_t stream) {
    const float* x      = (const float*)d_in[0];
    const int*   qw     = (const int*)d_in[1];
    const float* scales = (const float*)d_in[2];
    const float* bias   = (const float*)d_in[3];
    float*       out    = (float*)d_out;
    unsigned short* xT  = (unsigned short*)d_ws;   // 256 KB fragment-ordered x

    hipLaunchKernelGGL(xconv_kernel, dim3(64), dim3(256), 0, stream, x, xT);
    hipLaunchKernelGGL(qlin_kernel, dim3(OUT_F / BN), dim3(512), 0, stream,
                       xT, qw, scales, bias, out);
}

// Round 8
// 54.532 us; speedup vs baseline: 1.3264x; 1.3264x over previous
//
#include <hip/hip_runtime.h>

typedef __attribute__((ext_vector_type(8))) short short8;
typedef __attribute__((ext_vector_type(4))) float f32x4;
typedef __attribute__((ext_vector_type(4))) int   i32x4;

#define IN_F   4096
#define OUT_F  16384
#define NG     32
#define BK     128          // ints per chunk per row (512 B granule)
#define NCH    16           // chunks per K-half (2048/128)

// f32 -> bf16 round-to-nearest-even
static __device__ __forceinline__ short f2bf(float f) {
    union { float f; unsigned u; } c; c.f = f;
    unsigned u = c.u;
    u += 0x7FFF + ((u >> 16) & 1);
    return (short)(u >> 16);
}

// int8-range -> bf16 (exact for |v| <= 127)
static __device__ __forceinline__ short i2bf(int v) {
    union { float f; unsigned u; } c; c.f = (float)v;
    return (short)(c.u >> 16);
}

// Pre-pass: x[32][4096] f32 -> xT bf16 in MFMA-A-fragment order.
// xT layout: [t][h][ln][8] bf16, t = k/32, h = m-half, ln = l15*4 + l4.
__global__ __launch_bounds__(256)
void xconv_kernel(const float* __restrict__ x, unsigned short* __restrict__ xT) {
    const int g   = blockIdx.x * 256 + threadIdx.x;   // 16384 threads
    const int t   = g >> 7;
    const int rem = g & 127;
    const int h   = rem >> 6;
    const int ln  = rem & 63;
    const int l15 = ln >> 2;
    const int l4  = ln & 3;
    const float* src = x + (size_t)(16 * h + l15) * IN_F + t * 32 + l4 * 8;
    f32x4 a = *(const f32x4*)src;
    f32x4 b = *(const f32x4*)(src + 4);
    short8 o;
#pragma unroll
    for (int j = 0; j < 4; ++j) { o[j] = f2bf(a[j]); o[j + 4] = f2bf(b[j]); }
    *(short8*)(xT + (size_t)g * 8) = o;
}

// Main: 512 thr = 8 waves, block owns 32 out-cols, grid 512 (R6 config).
// wk = K-half, (wm,wn) = 16x16 tile. BK=128 (512B/row/interval), 2 LDS slots,
// depth-1 counted-vmcnt pipeline with stage issued at top of each interval.
__global__ __launch_bounds__(512, 4)
void qlin_kernel(const unsigned short* __restrict__ xT,
                 const int*   __restrict__ qw,
                 const float* __restrict__ scales,
                 const float* __restrict__ bias,
                 float*       __restrict__ out)
{
    __shared__ int lqw[2][2][32][BK];   // [wk][slot][row][int] = 64 KB

    const int tid  = threadIdx.x;
    const int wv   = tid >> 6;
    const int lane = tid & 63;
    const int l15  = lane & 15;
    const int l4   = lane >> 4;
    const int wk   = wv >> 2;         // K-half
    const int wm   = (wv >> 1) & 1;   // m-half
    const int wn   = wv & 1;          // n-half
    const int widx = wv & 3;
    const int col0 = blockIdx.x * 32;

    const int rowB = 16 * wn + l15;
    const int swzB = (rowB & 7) << 4;

    // --- stage chunk c of this wave's K-half into slot sl ---
    // 4 instrs/wave, each 1 KB = 2 rows x 512 B, LDS linear; global source
    // pre-swizzled by ((row&7)<<4) (read applies same XOR; rule #21).
    auto STAGE = [&](int c, int sl) {
        const size_t kbase = (size_t)wk * 2048 + (size_t)c * BK;
#pragma unroll
        for (int i = 0; i < 4; ++i) {
            const int p   = widx * 4 + i;            // 0..15
            const int row = 2 * p + (lane >> 5);
            const int byt = ((lane & 31) * 16) ^ ((row & 7) << 4);
            const char* src = (const char*)(qw + (size_t)(col0 + row) * IN_F + kbase) + byt;
            __builtin_amdgcn_global_load_lds(
                (const __attribute__((address_space(1))) unsigned int*)src,
                (__attribute__((address_space(3))) unsigned int*)&lqw[wk][sl][2 * p][0],
                16, 0, 0);
        }
    };

    // --- x fragments: 4 k-tiles per chunk, parked in registers, parity 2 ---
    const unsigned short* xgrp = xT + (size_t)(l15 * 4 + l4) * 8 + (size_t)wm * 512;
    short8 xa[2][4];
    auto XLOAD = [&](int c, int par) {
        const int t = wk * 64 + c * 4;
#pragma unroll
        for (int s = 0; s < 4; ++s)
            xa[par][s] = *(const short8*)(xgrp + (size_t)(t + s) * 1024);
    };

    // --- scales: one group per chunk; preload all 16 (static idx) ---
    const float* scr = scales + (size_t)(col0 + rowB) * NG + wk * 16;
    f32x4 sc4[4];
#pragma unroll
    for (int j = 0; j < 4; ++j) sc4[j] = *(const f32x4*)(scr + 4 * j);

    f32x4 acc = {0.f, 0.f, 0.f, 0.f};

    // --- compute chunk c from slot sl (static indices) ---
    auto COMPUTE = [&](int c, int sl, int par, float sc) {
        const char* lrow = (const char*)&lqw[wk][sl][rowB][0];
        f32x4 ag = {0.f, 0.f, 0.f, 0.f};
#pragma unroll
        for (int s = 0; s < 4; ++s) {
            const int off = (s * 128 + l4 * 32) ^ swzB;
            i32x4 q0 = *(const i32x4*)(lrow + off);
            i32x4 q1 = *(const i32x4*)(lrow + (off ^ 16));
            short8 bfr;
#pragma unroll
            for (int j = 0; j < 4; ++j) { bfr[j] = i2bf(q0[j]); bfr[j + 4] = i2bf(q1[j]); }
            ag = __builtin_amdgcn_mfma_f32_16x16x32_bf16(xa[par][s], bfr, ag, 0, 0, 0);
        }
#pragma unroll
        for (int r = 0; r < 4; ++r) acc[r] += sc * ag[r];
    };

    // --- prologue: stage(0) then x(0); vmcnt(4) drains stage(0), keeps x(0) ---
    STAGE(0, 0);
    asm volatile("" ::: "memory");     // pin: stage before x in VMEM issue order
    XLOAD(0, 0);
    asm volatile("s_waitcnt vmcnt(4)" ::: "memory");
    __builtin_amdgcn_s_barrier();
    __builtin_amdgcn_sched_barrier(0);

    // --- steady: {stage(i+1), x(i+1)} at top || compute(i); vmcnt(4) ---
#pragma unroll
    for (int i = 0; i <= 14; ++i) {
        STAGE(i + 1, (i + 1) & 1);
        asm volatile("" ::: "memory");
        XLOAD(i + 1, (i + 1) & 1);
        asm volatile("" ::: "memory");
        COMPUTE(i, i & 1, i & 1, sc4[i >> 2][i & 3]);
        asm volatile("s_waitcnt vmcnt(4)" ::: "memory");
        __builtin_amdgcn_s_barrier();
        __builtin_amdgcn_sched_barrier(0);
    }
    COMPUTE(15, 1, 1, sc4[3][3]);

    // --- epilogue: cross-wk reduce through aliased LDS ---
    __syncthreads();
    float* red = (float*)&lqw[0][0][0][0];    // [8][64][4] = 8 KB
    *(f32x4*)&red[(size_t)(wv * 64 + lane) * 4] = acc;
    __syncthreads();
    if (wv < 4) {
        const int col = col0 + rowB;
        const float bv = bias[col];
        f32x4 lo = *(const f32x4*)&red[(size_t)(wv * 64 + lane) * 4];
        f32x4 hi = *(const f32x4*)&red[(size_t)((wv + 4) * 64 + lane) * 4];
#pragma unroll
        for (int r = 0; r < 4; ++r)
            out[(size_t)(16 * wm + l4 * 4 + r) * OUT_F + col] = lo[r] + hi[r] + bv;
    }
}

extern "C" void kernel_launch(void* const* d_in, const int* in_sizes, int n_in,
                              void* d_out, int out_size, void* d_ws, size_t ws_size,
                              hipStream_t stream) {
    const float* x      = (const float*)d_in[0];
    const int*   qw     = (const int*)d_in[1];
    const float* scales = (const float*)d_in[2];
    const float* bias   = (const float*)d_in[3];
    float*       out    = (float*)d_out;
    unsigned short* xT  = (unsigned short*)d_ws;   // 256 KB fragment-ordered x

    hipLaunchKernelGGL(xconv_kernel, dim3(64), dim3(256), 0, stream, x, xT);
    hipLaunchKernelGGL(qlin_kernel, dim3(OUT_F / 32), dim3(512), 0, stream,
                       xT, qw, scales, bias, out);
}